// Round 4
// baseline (28.313 us; speedup 1.0000x reference)
//
#include <hip/hip_runtime.h>
#include <hip/hip_bf16.h>
#include <math.h>

#define NB_TASKS 20
#define CLASSES_PER_TASK 100
#define N_COLS (NB_TASKS * CLASSES_PER_TASK)   // 2000
#define N_F4   (N_COLS / 4)                    // 500
#define F4_PER_TASK (CLASSES_PER_TASK / 4)     // 25
#define INV_TEMP (1.0f / 5.0f)
#define ROWS_PER_BLOCK 4

__device__ __forceinline__ float rfl_f(float x) {
    return __int_as_float(__builtin_amdgcn_readfirstlane(__float_as_int(x)));
}

struct Top2 { int j1, j2; float w1, w2; };

// v: lane t (t<20) holds value for task t; lanes 20..63 hold -INF.
// Returns wave-uniform top-2 indices and softmax weights (scaled by coef).
__device__ __forceinline__ Top2 softmax_top2(float v, float coef, int lane) {
    // argmax, min-index tiebreak (== jax top_k tie rule); data lives in lanes 0..31
    float v1 = v; int i1 = lane;
    #pragma unroll
    for (int off = 16; off; off >>= 1) {
        float ov = __shfl_xor(v1, off);
        int   oj = __shfl_xor(i1, off);
        if (ov > v1 || (ov == v1 && oj < i1)) { v1 = ov; i1 = oj; }
    }
    // second argmax, excluding lane i1
    float v2 = (lane == i1) ? -INFINITY : v;
    int   i2 = lane;
    #pragma unroll
    for (int off = 16; off; off >>= 1) {
        float ov = __shfl_xor(v2, off);
        int   oj = __shfl_xor(i2, off);
        if (ov > v2 || (ov == v2 && oj < i2)) { v2 = ov; i2 = oj; }
    }
    // softmax denominator: exp((v - max)/T); -INF lanes contribute 0
    float ex  = __expf((v - v1) * INV_TEMP);
    float sum = ex;
    #pragma unroll
    for (int off = 16; off; off >>= 1)
        sum += __shfl_xor(sum, off);

    Top2 r;
    r.j1 = __builtin_amdgcn_readfirstlane(i1);
    r.j2 = __builtin_amdgcn_readfirstlane(i2);
    float w1 = coef / sum;                        // exp(0) = 1
    float w2 = __expf((v2 - v1) * INV_TEMP) * w1;
    r.w1 = rfl_f(w1);
    r.w2 = rfl_f(w2);
    return r;
}

__global__ __launch_bounds__(256) void mix_kernel(
    const float* __restrict__ gol,     // [B, 20]
    const float* __restrict__ gocls,   // [B, 2000]
    const float* __restrict__ dol,     // [B, 2000]
    const float* __restrict__ alpha_p, // [1]
    float* __restrict__ out,           // [B, 2000]
    int B)
{
    const int tid  = threadIdx.x;
    const int lane = tid & 63;
    const int b    = blockIdx.x * ROWS_PER_BLOCK + (tid >> 6);
    if (b >= B) return;

    const int grp = lane >> 4;   // 16-lane group: 0..3
    const int s   = lane & 15;

    const float4* din  = (const float4*)(dol + (size_t)b * N_COLS);
    float4*       dout = (float4*)(out + (size_t)b * N_COLS);
    const float*  grow = gocls + (size_t)b * N_COLS;

    // tiny loads needed by softmax — issue early
    const float a  = alpha_p[0];
    const float gv = (lane < NB_TASKS) ? gol[(size_t)b * NB_TASKS + lane] : -INFINITY;

    // --- zero-blast the whole output row: depends on NOTHING, overlaps the
    //     entire reduce+softmax phase. 80% of write traffic starts now. ---
    {
        const float4 z = {0.0f, 0.0f, 0.0f, 0.0f};
        #pragma unroll
        for (int i = 0; i < (N_F4 + 63) / 64; ++i) {
            const int f = lane + 64 * i;
            if (f < N_F4) dout[f] = z;
        }
    }

    // --- per-task max over 100 classes, 4 tasks per iteration ---
    // group g handles task 4k+g; 25 float4 per task: lanes read [s] and [16+s] (s<9)
    float cv = -INFINITY;
    #pragma unroll
    for (int k = 0; k < 5; ++k) {
        const float4* p = (const float4*)(grow + (4 * k + grp) * CLASSES_PER_TASK);
        float4 v0 = p[s];
        float m = fmaxf(fmaxf(v0.x, v0.y), fmaxf(v0.z, v0.w));
        if (s < 25 - 16) {
            float4 v1 = p[16 + s];
            m = fmaxf(m, fmaxf(fmaxf(v1.x, v1.y), fmaxf(v1.z, v1.w)));
        }
        #pragma unroll
        for (int off = 8; off; off >>= 1)          // butterfly within 16-lane group
            m = fmaxf(m, __shfl_xor(m, off));
        float g2 = __shfl(m, (lane & 3) << 4);     // lane 4k+g <- group g's max
        if ((lane >> 2) == k) cv = g2;             // lanes 0..19 collect task maxes
    }

    // --- both paths: wave-uniform top-2 weights ---
    const Top2 pa = softmax_top2(gv, a,        lane);
    const Top2 pb = softmax_top2(cv, 1.0f - a, lane);

    // ensure all zero-stores have landed before overwriting top-k regions
    asm volatile("s_waitcnt vmcnt(0)" ::: "memory");

    // --- weighted pass over the <=4 distinct top-k tasks (wave-uniform) ---
    int   js[4] = {pa.j1, pa.j2, pb.j1, pb.j2};
    float ws[4] = {pa.w1, pa.w2, pb.w1, pb.w2};

    #pragma unroll
    for (int i = 0; i < 4; ++i) {
        bool first = true;
        #pragma unroll
        for (int k = 0; k < i; ++k) first = first && (js[k] != js[i]);
        if (first) {
            float w = ws[i];
            #pragma unroll
            for (int k = i + 1; k < 4; ++k) w += (js[k] == js[i]) ? ws[k] : 0.0f;
            if (lane < F4_PER_TASK) {
                const int f = js[i] * F4_PER_TASK + lane;
                float4 v = din[f];
                float4 r = {v.x * w, v.y * w, v.z * w, v.w * w};
                dout[f] = r;
            }
        }
    }
}

extern "C" void kernel_launch(void* const* d_in, const int* in_sizes, int n_in,
                              void* d_out, int out_size, void* d_ws, size_t ws_size,
                              hipStream_t stream) {
    const float* gol   = (const float*)d_in[0];
    const float* gocls = (const float*)d_in[1];
    const float* dol   = (const float*)d_in[2];
    const float* alpha = (const float*)d_in[3];
    float* out = (float*)d_out;

    const int B = in_sizes[0] / NB_TASKS;  // 8192

    const int grid = (B + ROWS_PER_BLOCK - 1) / ROWS_PER_BLOCK;
    hipLaunchKernelGGL(mix_kernel, dim3(grid), dim3(256), 0, stream,
                       gol, gocls, dol, alpha, out, B);
}